// Round 1
// baseline (435.272 us; speedup 1.0000x reference)
//
#include <hip/hip_runtime.h>
#include <stdint.h>

#define NBATCH 16
#define HW_ (1 << 20)          // 1024*1024 per batch
#define NBPB 256               // blocks per batch for scan kernels
#define TPB 256
#define EPB (HW_ / NBPB)       // 4096 elements per block
#define V4PT (EPB / (TPB * 4)) // 4 float4 per thread

struct BParams {
    unsigned int k;       // n_train for this batch
    unsigned int bin1;    // selected level-1 bin (top16 - 0x3F40)
    unsigned int G1;      // count with top16 bin > bin1
    unsigned int r;       // k - G1
    unsigned int sstar;   // threshold score bits
    unsigned int T;       // ties to take at sstar
    unsigned int mode;    // 0 = no train, 1 = thresh (all ties), 2 = thresh + idx cut
    unsigned int bin3;    // index-select bin
    unsigned int T2;      // remaining within bin3
    unsigned int idxcut;  // train if score==sstar && idx <= idxcut
};

__device__ __forceinline__ unsigned int score_bits(float p, int m) {
    bool correct = (p > 0.5f) == (m == 1);
    float conf = fmaxf(p, 1.0f - p);
    float base = correct ? ((conf > 0.85f) ? 1.0f : 2.0f)
                         : ((conf > 0.85f) ? 4.0f : 3.0f);
    float bonus = (conf - 0.5f) * 0.5f;   // exact in f32 (Sterbenz + *0.5)
    float s = correct ? (base - bonus) : (base + bonus);
    return __float_as_uint(s);            // positive floats: bits order == value order
}

// Pass 1: 512-bin histogram on (score_bits >> 16) - 0x3F40, plus annotated count.
__global__ void k_hist1(const float4* __restrict__ pred4, const int4* __restrict__ mask4,
                        unsigned int* __restrict__ hist1, unsigned int* __restrict__ nannot) {
    __shared__ unsigned int lh[512];
    __shared__ unsigned int lann;
    int b = blockIdx.x / NBPB;
    int blk = blockIdx.x % NBPB;
    for (int i = threadIdx.x; i < 512; i += TPB) lh[i] = 0;
    if (threadIdx.x == 0) lann = 0;
    __syncthreads();
    unsigned int myann = 0;
    int l4base = blk * (EPB / 4);
    for (int j = 0; j < V4PT; j++) {
        int i4l = l4base + j * TPB + threadIdx.x;
        size_t g4 = (size_t)b * (HW_ / 4) + i4l;
        float4 p = pred4[g4];
        int4 m = mask4[g4];
        float pa[4] = {p.x, p.y, p.z, p.w};
        int ma[4] = {m.x, m.y, m.z, m.w};
#pragma unroll
        for (int l = 0; l < 4; l++) {
            if (ma[l] != 2) {
                myann++;
                unsigned int sb = score_bits(pa[l], ma[l]);
                int bin = (int)(sb >> 16) - 0x3F40;
                bin = min(max(bin, 0), 511);
                atomicAdd(&lh[bin], 1u);
            }
        }
    }
    atomicAdd(&lann, myann);
    __syncthreads();
    for (int i = threadIdx.x; i < 512; i += TPB)
        if (lh[i]) atomicAdd(&hist1[b * 512 + i], lh[i]);
    if (threadIdx.x == 0) atomicAdd(&nannot[b], lann);
}

// Find level-1 bin containing the k-th largest.
__global__ void k_find1(const unsigned int* __restrict__ hist1,
                        const unsigned int* __restrict__ nannot, BParams* prm) {
    int b = blockIdx.x;
    if (threadIdx.x != 0) return;
    unsigned int n = nannot[b];
    unsigned int k = (unsigned int)(int)((float)n * 0.5f);  // matches astype(f32)*0.5 -> int32
    BParams P = {};
    P.k = k;
    if (k == 0) { P.mode = 0; P.sstar = 0xFFFFFFFFu; P.idxcut = 0; prm[b] = P; return; }
    unsigned int cum = 0;
    int bin = 511;
    for (; bin > 0; bin--) {
        unsigned int h = hist1[b * 512 + bin];
        if (cum + h >= k) break;
        cum += h;
    }
    P.bin1 = (unsigned int)bin;
    P.G1 = cum;
    P.r = k - cum;
    P.mode = 1;  // provisional
    prm[b] = P;
}

// Pass 2: 65536-bin histogram on low-16 score bits within bin1.
__global__ void k_hist2(const float4* __restrict__ pred4, const int4* __restrict__ mask4,
                        const BParams* __restrict__ prm, unsigned int* __restrict__ hist2) {
    int b = blockIdx.x / NBPB;
    BParams P = prm[b];
    if (P.mode == 0) return;
    unsigned int target_top = P.bin1 + 0x3F40u;
    int blk = blockIdx.x % NBPB;
    int l4base = blk * (EPB / 4);
    for (int j = 0; j < V4PT; j++) {
        int i4l = l4base + j * TPB + threadIdx.x;
        size_t g4 = (size_t)b * (HW_ / 4) + i4l;
        float4 p = pred4[g4];
        int4 m = mask4[g4];
        float pa[4] = {p.x, p.y, p.z, p.w};
        int ma[4] = {m.x, m.y, m.z, m.w};
#pragma unroll
        for (int l = 0; l < 4; l++) {
            if (ma[l] != 2) {
                unsigned int sb = score_bits(pa[l], ma[l]);
                if ((sb >> 16) == target_top)
                    atomicAdd(&hist2[(size_t)b * 65536 + (sb & 0xFFFFu)], 1u);
            }
        }
    }
}

// Find exact threshold score bits s*.
__global__ void k_find2(const unsigned int* __restrict__ hist2, BParams* prm) {
    int b = blockIdx.x;
    __shared__ unsigned int csum[256];
    __shared__ unsigned int binv[256];
    __shared__ unsigned int sh_cum;
    __shared__ int sh_sel;
    BParams P = prm[b];
    if (P.mode == 0) return;
    const unsigned int* h = hist2 + (size_t)b * 65536;
    int t = threadIdx.x;
    unsigned int s = 0;
    for (int j = 0; j < 256; j++) s += h[t * 256 + j];
    csum[t] = s;
    __syncthreads();
    if (t == 0) {
        unsigned int cum = 0;
        int c = 255;
        for (; c > 0; c--) {
            if (cum + csum[c] >= P.r) break;
            cum += csum[c];
        }
        sh_sel = c;
        sh_cum = cum;
    }
    __syncthreads();
    int c = sh_sel;
    binv[t] = h[c * 256 + t];
    __syncthreads();
    if (t == 0) {
        unsigned int cum = sh_cum;
        int v = 255;
        for (; v > 0; v--) {
            if (cum + binv[v] >= P.r) break;
            cum += binv[v];
        }
        unsigned int E = binv[v];
        unsigned int T = P.r - cum;  // 1..E
        P.sstar = ((P.bin1 + 0x3F40u) << 16) | (unsigned int)(c * 256 + v);
        if (T == E) { P.mode = 1; P.idxcut = 0xFFFFFFFFu; }
        else        { P.mode = 2; P.T = T; P.idxcut = 0u; }
        prm[b] = P;
    }
}

// Pass 3 (only mode==2 batches): histogram flat index >> 10 of elements with score==s*.
__global__ void k_hist3(const float4* __restrict__ pred4, const int4* __restrict__ mask4,
                        const BParams* __restrict__ prm, unsigned int* __restrict__ hist3) {
    int b = blockIdx.x / NBPB;
    BParams P = prm[b];
    if (P.mode != 2) return;
    int blk = blockIdx.x % NBPB;
    int l4base = blk * (EPB / 4);
    for (int j = 0; j < V4PT; j++) {
        int i4l = l4base + j * TPB + threadIdx.x;
        size_t g4 = (size_t)b * (HW_ / 4) + i4l;
        float4 p = pred4[g4];
        int4 m = mask4[g4];
        float pa[4] = {p.x, p.y, p.z, p.w};
        int ma[4] = {m.x, m.y, m.z, m.w};
#pragma unroll
        for (int l = 0; l < 4; l++) {
            if (ma[l] != 2 && score_bits(pa[l], ma[l]) == P.sstar) {
                unsigned int i = (unsigned int)(i4l * 4 + l);
                atomicAdd(&hist3[b * 1024 + (i >> 10)], 1u);
            }
        }
    }
}

__global__ void k_find3(const unsigned int* __restrict__ hist3, BParams* prm) {
    int b = blockIdx.x;
    BParams P = prm[b];
    if (P.mode != 2) return;
    __shared__ unsigned int lh[1024];
    for (int i = threadIdx.x; i < 1024; i += TPB) lh[i] = hist3[b * 1024 + i];
    __syncthreads();
    if (threadIdx.x == 0) {
        unsigned int cum = 0;
        int bin = 0;
        for (; bin < 1023; bin++) {
            if (cum + lh[bin] >= P.T) break;
            cum += lh[bin];
        }
        P.bin3 = (unsigned int)bin;
        P.T2 = P.T - cum;
        prm[b] = P;
    }
}

// Pass 4: only the 1024-element index window [bin3*1024, +1024).
__global__ void k_hist4(const float* __restrict__ pred, const int* __restrict__ mask,
                        const BParams* __restrict__ prm, unsigned int* __restrict__ hist4) {
    int b = blockIdx.x;
    BParams P = prm[b];
    if (P.mode != 2) return;
    for (int l = 0; l < 4; l++) {
        unsigned int i = P.bin3 * 1024 + l * TPB + threadIdx.x;
        size_t g = (size_t)b * HW_ + i;
        int m = mask[g];
        if (m != 2 && score_bits(pred[g], m) == P.sstar)
            atomicAdd(&hist4[b * 1024 + (i & 1023u)], 1u);
    }
}

__global__ void k_find4(const unsigned int* __restrict__ hist4, BParams* prm) {
    int b = blockIdx.x;
    BParams P = prm[b];
    if (P.mode != 2) return;
    __shared__ unsigned int lh[1024];
    for (int i = threadIdx.x; i < 1024; i += TPB) lh[i] = hist4[b * 1024 + i];
    __syncthreads();
    if (threadIdx.x == 0) {
        unsigned int cum = 0;
        int pos = 0;
        for (; pos < 1023; pos++) {
            if (cum + lh[pos] >= P.T2) break;
            cum += lh[pos];
        }
        P.idxcut = P.bin3 * 1024 + (unsigned int)pos;
        prm[b] = P;
    }
}

// Final pass: masks + BCE partial sums.
__global__ void k_final(const float4* __restrict__ pred4, const int4* __restrict__ mask4,
                        const BParams* __restrict__ prm, float* __restrict__ out,
                        float* __restrict__ partials) {
    int b = blockIdx.x / NBPB;
    int blk = blockIdx.x % NBPB;
    BParams P = prm[b];
    __shared__ float red[TPB];
    float acc = 0.0f;
    float* trout = out + 1;
    float* hoout = out + 1 + (size_t)NBATCH * HW_;
    int l4base = blk * (EPB / 4);
    for (int j = 0; j < V4PT; j++) {
        int i4l = l4base + j * TPB + threadIdx.x;
        size_t g4 = (size_t)b * (HW_ / 4) + i4l;
        float4 p = pred4[g4];
        int4 m = mask4[g4];
        float pa[4] = {p.x, p.y, p.z, p.w};
        int ma[4] = {m.x, m.y, m.z, m.w};
#pragma unroll
        for (int l = 0; l < 4; l++) {
            bool ann = (ma[l] != 2);
            bool tr = false;
            if (ann && P.mode != 0) {
                unsigned int sb = score_bits(pa[l], ma[l]);
                unsigned int i = (unsigned int)(i4l * 4 + l);
                tr = (sb > P.sstar) || (sb == P.sstar && i <= P.idxcut);
            }
            size_t g = g4 * 4 + (size_t)l;
            trout[g] = tr ? 1.0f : 0.0f;
            hoout[g] = (ann && !tr) ? 1.0f : 0.0f;
            if (tr) {
                float pc = fminf(fmaxf(pa[l], 1e-7f), 1.0f - 1e-7f);
                acc += (ma[l] == 1) ? -logf(pc) : -logf(1.0f - pc);
            }
        }
    }
    red[threadIdx.x] = acc;
    __syncthreads();
    for (int off = TPB / 2; off > 0; off >>= 1) {
        if (threadIdx.x < off) red[threadIdx.x] += red[threadIdx.x + off];
        __syncthreads();
    }
    if (threadIdx.x == 0) partials[blockIdx.x] = red[0];
}

__global__ void k_loss(const float* __restrict__ partials, const BParams* __restrict__ prm,
                       float* __restrict__ out) {
    __shared__ double red[TPB];
    double s = 0.0;
    for (int i = threadIdx.x; i < NBATCH * NBPB; i += TPB) s += (double)partials[i];
    red[threadIdx.x] = s;
    __syncthreads();
    for (int off = TPB / 2; off > 0; off >>= 1) {
        if (threadIdx.x < off) red[threadIdx.x] += red[threadIdx.x + off];
        __syncthreads();
    }
    if (threadIdx.x == 0) {
        unsigned long long den = 0;
        for (int b = 0; b < NBATCH; b++) den += prm[b].k;
        float denf = (float)den + 1e-7f;
        out[0] = (float)red[0] / denf;
    }
}

extern "C" void kernel_launch(void* const* d_in, const int* in_sizes, int n_in,
                              void* d_out, int out_size, void* d_ws, size_t ws_size,
                              hipStream_t stream) {
    const float* pred = (const float*)d_in[0];
    const int* mask = (const int*)d_in[1];
    const float4* pred4 = (const float4*)pred;
    const int4* mask4 = (const int4*)mask;
    float* out = (float*)d_out;

    // workspace layout (uint32 words)
    unsigned int* hist1 = (unsigned int*)d_ws;            // 16*512
    unsigned int* hist2 = hist1 + NBATCH * 512;           // 16*65536
    unsigned int* hist3 = hist2 + NBATCH * 65536;         // 16*1024
    unsigned int* hist4 = hist3 + NBATCH * 1024;          // 16*1024
    unsigned int* nannot = hist4 + NBATCH * 1024;         // 16
    BParams* prm = (BParams*)(nannot + NBATCH);           // 16 structs
    float* partials = (float*)((char*)(prm + NBATCH));    // NBATCH*NBPB floats

    size_t zero_bytes = (size_t)(NBATCH * 512 + NBATCH * 65536 + NBATCH * 1024 +
                                 NBATCH * 1024 + NBATCH) * 4;
    hipMemsetAsync(d_ws, 0, zero_bytes, stream);

    dim3 big(NBATCH * NBPB), one(NBATCH), tpb(TPB);
    k_hist1<<<big, tpb, 0, stream>>>(pred4, mask4, hist1, nannot);
    k_find1<<<one, dim3(64), 0, stream>>>(hist1, nannot, prm);
    k_hist2<<<big, tpb, 0, stream>>>(pred4, mask4, prm, hist2);
    k_find2<<<one, tpb, 0, stream>>>(hist2, prm);
    k_hist3<<<big, tpb, 0, stream>>>(pred4, mask4, prm, hist3);
    k_find3<<<one, tpb, 0, stream>>>(hist3, prm);
    k_hist4<<<one, tpb, 0, stream>>>(pred, mask, prm, hist4);
    k_find4<<<one, tpb, 0, stream>>>(hist4, prm);
    k_final<<<big, tpb, 0, stream>>>(pred4, mask4, prm, out, partials);
    k_loss<<<dim3(1), tpb, 0, stream>>>(partials, prm, out);
}

// Round 2
// 322.414 us; speedup vs baseline: 1.3500x; 1.3500x over previous
//
#include <hip/hip_runtime.h>
#include <stdint.h>

#define NBATCH 16
#define HW_ (1 << 20)            // 1024*1024 per batch
#define TPB 256

#define NBPB_H 128               // blocks per batch for scan kernels
#define EPB_H (HW_ / NBPB_H)     // 8192 elements per block
#define ITER_H (EPB_H / (TPB * 4)) // 8 float4 per thread

#define NBPB_F 256               // blocks per batch for final kernel
#define FCHUNK (HW_ / NBPB_F)    // 4096 elements per block

#define CAND_CAP 65536           // candidate slots per batch (aliased on hist2)

typedef float f4v __attribute__((ext_vector_type(4)));

struct BParams {
    unsigned int k;       // n_train for this batch
    unsigned int bin1;    // selected level-1 bin (top16 - 0x3F40)
    unsigned int G1;      // count with top16 bin > bin1
    unsigned int r;       // k - G1
    unsigned int sstar;   // threshold score bits
    unsigned int T;       // ties to take at sstar
    unsigned int mode;    // 0 = no train, 1 = thresh (all ties), 2 = thresh + idx cut
    unsigned int idxcut;  // train if score==sstar && idx <= idxcut
};

__device__ __forceinline__ unsigned int score_bits(float p, int m) {
    bool correct = (p > 0.5f) == (m == 1);
    float conf = fmaxf(p, 1.0f - p);
    float base = correct ? ((conf > 0.85f) ? 1.0f : 2.0f)
                         : ((conf > 0.85f) ? 4.0f : 3.0f);
    float bonus = (conf - 0.5f) * 0.5f;   // exact in f32 (Sterbenz + *0.5)
    float s = correct ? (base - bonus) : (base + bonus);
    return __float_as_uint(s);            // positive floats: bits order == value order
}

// Pass 1: 512-bin histogram on (score_bits >> 16) - 0x3F40, with 8 LDS sub-hists.
__global__ void k_hist1(const float4* __restrict__ pred4, const int4* __restrict__ mask4,
                        unsigned int* __restrict__ hist1, unsigned int* __restrict__ nannot) {
    __shared__ unsigned int lh[512 * 8];
    __shared__ unsigned int lann;
    int b = blockIdx.x / NBPB_H;
    int blk = blockIdx.x % NBPB_H;
    for (int i = threadIdx.x; i < 512 * 8; i += TPB) lh[i] = 0;
    if (threadIdx.x == 0) lann = 0;
    __syncthreads();
    int sub = threadIdx.x & 7;
    unsigned int myann = 0;
    int l4base = blk * (EPB_H / 4);
    for (int j = 0; j < ITER_H; j++) {
        int i4l = l4base + j * TPB + threadIdx.x;
        size_t g4 = (size_t)b * (HW_ / 4) + i4l;
        float4 p = pred4[g4];
        int4 m = mask4[g4];
        float pa[4] = {p.x, p.y, p.z, p.w};
        int ma[4] = {m.x, m.y, m.z, m.w};
#pragma unroll
        for (int l = 0; l < 4; l++) {
            if (ma[l] != 2) {
                myann++;
                unsigned int sb = score_bits(pa[l], ma[l]);
                int bin = (int)(sb >> 16) - 0x3F40;
                bin = min(max(bin, 0), 511);
                atomicAdd(&lh[bin * 8 + sub], 1u);
            }
        }
    }
    atomicAdd(&lann, myann);
    __syncthreads();
    for (int i = threadIdx.x; i < 512; i += TPB) {
        unsigned int s = 0;
#pragma unroll
        for (int q = 0; q < 8; q++) s += lh[i * 8 + q];
        if (s) atomicAdd(&hist1[b * 512 + i], s);
    }
    if (threadIdx.x == 0) atomicAdd(&nannot[b], lann);
}

// Parallel find of level-1 bin: LDS suffix scan over 512 bins.
__global__ void k_find1(const unsigned int* __restrict__ hist1,
                        const unsigned int* __restrict__ nannot, BParams* prm) {
    int b = blockIdx.x;
    int t = threadIdx.x;
    __shared__ unsigned int sfx[513];
    __shared__ unsigned int sk;
    sfx[t] = hist1[b * 512 + t];
    sfx[t + 256] = hist1[b * 512 + t + 256];
    if (t == 0) {
        sfx[512] = 0;
        unsigned int n = nannot[b];
        sk = (unsigned int)(int)((float)n * 0.5f);  // matches astype(f32)*0.5 -> int32
    }
    __syncthreads();
    for (int off = 1; off < 512; off <<= 1) {
        unsigned int a0 = (t + off < 512) ? sfx[t + off] : 0u;
        unsigned int a1 = (t + 256 + off < 512) ? sfx[t + 256 + off] : 0u;
        __syncthreads();
        sfx[t] += a0;
        sfx[t + 256] += a1;
        __syncthreads();
    }
    unsigned int k = sk;
    if (k == 0) {
        if (t == 0) {
            BParams P = {};
            P.mode = 0; P.sstar = 0xFFFFFFFFu;
            prm[b] = P;
        }
        return;
    }
#pragma unroll
    for (int h = 0; h < 2; h++) {
        int i = t + h * 256;
        if (sfx[i] >= k && sfx[i + 1] < k) {
            BParams P = {};
            P.k = k;
            P.bin1 = (unsigned int)i;
            P.G1 = sfx[i + 1];
            P.r = k - sfx[i + 1];
            P.mode = 1;
            prm[b] = P;
        }
    }
}

// Pass 2: 65536-bin histogram on low-16 score bits within bin1 (sparse, global atomics).
__global__ void k_hist2(const float4* __restrict__ pred4, const int4* __restrict__ mask4,
                        const BParams* __restrict__ prm, unsigned int* __restrict__ hist2) {
    int b = blockIdx.x / NBPB_H;
    BParams P = prm[b];
    if (P.mode == 0) return;
    unsigned int target_top = P.bin1 + 0x3F40u;
    int blk = blockIdx.x % NBPB_H;
    int l4base = blk * (EPB_H / 4);
    for (int j = 0; j < ITER_H; j++) {
        int i4l = l4base + j * TPB + threadIdx.x;
        size_t g4 = (size_t)b * (HW_ / 4) + i4l;
        float4 p = pred4[g4];
        int4 m = mask4[g4];
        float pa[4] = {p.x, p.y, p.z, p.w};
        int ma[4] = {m.x, m.y, m.z, m.w};
#pragma unroll
        for (int l = 0; l < 4; l++) {
            if (ma[l] != 2) {
                unsigned int sb = score_bits(pa[l], ma[l]);
                if ((sb >> 16) == target_top)
                    atomicAdd(&hist2[(size_t)b * 65536 + (sb & 0xFFFFu)], 1u);
            }
        }
    }
}

// Find exact threshold score bits s* — vectorized row sums + LDS suffix scans.
__global__ void k_find2(const unsigned int* __restrict__ hist2, BParams* prm) {
    int b = blockIdx.x;
    BParams P = prm[b];
    if (P.mode == 0) return;
    int t = threadIdx.x;
    const unsigned int* h = hist2 + (size_t)b * 65536;
    __shared__ unsigned int sfx[257];
    __shared__ int sh_c;
    __shared__ unsigned int sh_cum;
    // coarse sums: thread t sums its own 256-bin row with uint4 loads
    {
        const uint4* h4 = (const uint4*)(h + t * 256);
        unsigned int s = 0;
        for (int j = 0; j < 64; j++) {
            uint4 v = h4[j];
            s += v.x + v.y + v.z + v.w;
        }
        sfx[t] = s;
        if (t == 0) sfx[256] = 0;
    }
    __syncthreads();
    for (int off = 1; off < 256; off <<= 1) {
        unsigned int a = (t + off < 256) ? sfx[t + off] : 0u;
        __syncthreads();
        sfx[t] += a;
        __syncthreads();
    }
    if (sfx[t] >= P.r && sfx[t + 1] < P.r) { sh_c = t; sh_cum = sfx[t + 1]; }
    __syncthreads();
    int c = sh_c;
    unsigned int r2 = P.r - sh_cum;       // remaining within coarse bin c
    unsigned int fv = h[c * 256 + t];     // coalesced
    __syncthreads();
    sfx[t] = fv;
    if (t == 0) sfx[256] = 0;
    __syncthreads();
    for (int off = 1; off < 256; off <<= 1) {
        unsigned int a = (t + off < 256) ? sfx[t + off] : 0u;
        __syncthreads();
        sfx[t] += a;
        __syncthreads();
    }
    if (sfx[t] >= r2 && sfx[t + 1] < r2) {
        unsigned int E = sfx[t] - sfx[t + 1];
        unsigned int T = r2 - sfx[t + 1];  // 1..E
        P.sstar = ((P.bin1 + 0x3F40u) << 16) | (unsigned int)(c * 256 + t);
        if (T == E) { P.mode = 1; P.idxcut = 0xFFFFFFFFu; }
        else        { P.mode = 2; P.T = T; P.idxcut = 0u; }
        prm[b] = P;
    }
}

// Collect flat indices of exact ties (mode==2 batches only).
__global__ void k_collect(const float4* __restrict__ pred4, const int4* __restrict__ mask4,
                          const BParams* __restrict__ prm, unsigned int* __restrict__ cand_cnt,
                          unsigned int* __restrict__ cand_idx) {
    int b = blockIdx.x / NBPB_H;
    BParams P = prm[b];
    if (P.mode != 2) return;
    int blk = blockIdx.x % NBPB_H;
    int l4base = blk * (EPB_H / 4);
    for (int j = 0; j < ITER_H; j++) {
        int i4l = l4base + j * TPB + threadIdx.x;
        size_t g4 = (size_t)b * (HW_ / 4) + i4l;
        float4 p = pred4[g4];
        int4 m = mask4[g4];
        float pa[4] = {p.x, p.y, p.z, p.w};
        int ma[4] = {m.x, m.y, m.z, m.w};
#pragma unroll
        for (int l = 0; l < 4; l++) {
            if (ma[l] != 2 && score_bits(pa[l], ma[l]) == P.sstar) {
                unsigned int pos = atomicAdd(&cand_cnt[b], 1u);
                if (pos < CAND_CAP)
                    cand_idx[(size_t)b * CAND_CAP + pos] = (unsigned int)(i4l * 4 + l);
            }
        }
    }
}

// Select T-th smallest tie index (E is tiny; O(E^2/256) broadcast reads).
__global__ void k_select(const unsigned int* __restrict__ cand_cnt,
                         const unsigned int* __restrict__ cand_idx, BParams* prm) {
    int b = blockIdx.x;
    BParams P = prm[b];
    if (P.mode != 2) return;
    unsigned int E = cand_cnt[b];
    if (E > CAND_CAP) E = CAND_CAP;
    const unsigned int* ci = cand_idx + (size_t)b * CAND_CAP;
    for (unsigned int i = threadIdx.x; i < E; i += TPB) {
        unsigned int vi = ci[i];
        unsigned int cnt = 0;
        for (unsigned int j = 0; j < E; j++) cnt += (ci[j] < vi) ? 1u : 0u;
        if (cnt == P.T - 1) prm[b].idxcut = vi;  // rank T-1 (0-based): T-th smallest
    }
}

// Final pass: masks (LDS-staged, aligned float4 writes) + BCE partial sums.
__global__ void k_final(const float4* __restrict__ pred4, const int4* __restrict__ mask4,
                        const BParams* __restrict__ prm, float* __restrict__ out,
                        float* __restrict__ partials) {
    int b = blockIdx.x / NBPB_F;
    int blk = blockIdx.x % NBPB_F;
    BParams P = prm[b];
    __shared__ float ltr[FCHUNK];
    __shared__ float lho[FCHUNK];
    __shared__ float red[TPB];
    float acc = 0.0f;
    int ibase = blk * FCHUNK;  // element base within batch
    for (int j = 0; j < FCHUNK / (TPB * 4); j++) {   // 4 iterations
        int li4 = j * TPB + threadIdx.x;             // local float4 idx [0,1024)
        size_t g4 = (size_t)b * (HW_ / 4) + (ibase / 4) + li4;
        float4 p = pred4[g4];
        int4 m = mask4[g4];
        float pa[4] = {p.x, p.y, p.z, p.w};
        int ma[4] = {m.x, m.y, m.z, m.w};
#pragma unroll
        for (int l = 0; l < 4; l++) {
            bool ann = (ma[l] != 2);
            bool tr = false;
            if (ann && P.mode != 0) {
                unsigned int sb = score_bits(pa[l], ma[l]);
                unsigned int i = (unsigned int)(ibase + li4 * 4 + l);
                tr = (sb > P.sstar) || (sb == P.sstar && i <= P.idxcut);
            }
            ltr[li4 * 4 + l] = tr ? 1.0f : 0.0f;
            lho[li4 * 4 + l] = (ann && !tr) ? 1.0f : 0.0f;
            if (tr) {
                float pc = fminf(fmaxf(pa[l], 1e-7f), 1.0f - 1e-7f);
                acc += (ma[l] == 1) ? -__logf(pc) : -__logf(1.0f - pc);
            }
        }
    }
    __syncthreads();
    // out layout: out[0]=loss, train at out[1 .. 1+16M), holdout next.
    float* trout = out + 1;
    float* hoout = out + 1 + (size_t)NBATCH * HW_;
    size_t Gbase = (size_t)b * HW_ + (size_t)ibase;
    // bulk: aligned float4 stores covering local elems [3, 4095)
    for (int v = threadIdx.x; v < FCHUNK / 4 - 1; v += TPB) {
        int e = 3 + 4 * v;
        f4v tv = { ltr[e], ltr[e + 1], ltr[e + 2], ltr[e + 3] };
        f4v hv = { lho[e], lho[e + 1], lho[e + 2], lho[e + 3] };
        __builtin_nontemporal_store(tv, (f4v*)(trout + Gbase + e));
        __builtin_nontemporal_store(hv, (f4v*)(hoout + Gbase + e));
    }
    if (threadIdx.x < 3) {   // head elems 0,1,2
        trout[Gbase + threadIdx.x] = ltr[threadIdx.x];
        hoout[Gbase + threadIdx.x] = lho[threadIdx.x];
    }
    if (threadIdx.x == 3) {  // tail elem 4095
        trout[Gbase + FCHUNK - 1] = ltr[FCHUNK - 1];
        hoout[Gbase + FCHUNK - 1] = lho[FCHUNK - 1];
    }
    red[threadIdx.x] = acc;
    __syncthreads();
    for (int off = TPB / 2; off > 0; off >>= 1) {
        if (threadIdx.x < off) red[threadIdx.x] += red[threadIdx.x + off];
        __syncthreads();
    }
    if (threadIdx.x == 0) partials[blockIdx.x] = red[0];
}

__global__ void k_loss(const float* __restrict__ partials, const BParams* __restrict__ prm,
                       float* __restrict__ out) {
    __shared__ double red[TPB];
    double s = 0.0;
    for (int i = threadIdx.x; i < NBATCH * NBPB_F; i += TPB) s += (double)partials[i];
    red[threadIdx.x] = s;
    __syncthreads();
    for (int off = TPB / 2; off > 0; off >>= 1) {
        if (threadIdx.x < off) red[threadIdx.x] += red[threadIdx.x + off];
        __syncthreads();
    }
    if (threadIdx.x == 0) {
        unsigned long long den = 0;
        for (int b = 0; b < NBATCH; b++) den += prm[b].k;
        float denf = (float)den + 1e-7f;
        out[0] = (float)red[0] / denf;
    }
}

extern "C" void kernel_launch(void* const* d_in, const int* in_sizes, int n_in,
                              void* d_out, int out_size, void* d_ws, size_t ws_size,
                              hipStream_t stream) {
    const float* pred = (const float*)d_in[0];
    const int* mask = (const int*)d_in[1];
    const float4* pred4 = (const float4*)pred;
    const int4* mask4 = (const int4*)mask;
    float* out = (float*)d_out;

    // workspace layout (uint32 words); zeroed region first
    unsigned int* hist1 = (unsigned int*)d_ws;            // 16*512
    unsigned int* hist2 = hist1 + NBATCH * 512;           // 16*65536
    unsigned int* nannot = hist2 + NBATCH * 65536;        // 16
    unsigned int* cand_cnt = nannot + NBATCH;             // 16
    BParams* prm = (BParams*)(cand_cnt + NBATCH);         // 16 structs
    float* partials = (float*)(prm + NBATCH);             // 16*256 floats
    // cand_idx aliases hist2 (hist2 is dead after k_find2)
    unsigned int* cand_idx = hist2;

    size_t zero_bytes = (size_t)(NBATCH * 512 + NBATCH * 65536 + NBATCH + NBATCH) * 4;
    hipMemsetAsync(d_ws, 0, zero_bytes, stream);

    dim3 scan(NBATCH * NBPB_H), fin(NBATCH * NBPB_F), one(NBATCH), tpb(TPB);
    k_hist1<<<scan, tpb, 0, stream>>>(pred4, mask4, hist1, nannot);
    k_find1<<<one, tpb, 0, stream>>>(hist1, nannot, prm);
    k_hist2<<<scan, tpb, 0, stream>>>(pred4, mask4, prm, hist2);
    k_find2<<<one, tpb, 0, stream>>>(hist2, prm);
    k_collect<<<scan, tpb, 0, stream>>>(pred4, mask4, prm, cand_cnt, cand_idx);
    k_select<<<one, tpb, 0, stream>>>(cand_cnt, cand_idx, prm);
    k_final<<<fin, tpb, 0, stream>>>(pred4, mask4, prm, out, partials);
    k_loss<<<dim3(1), tpb, 0, stream>>>(partials, prm, out);
}